// Round 1
// baseline (206.956 us; speedup 1.0000x reference)
//
#include <hip/hip_runtime.h>
#include <utility>
#include <type_traits>

// ============================================================================
// Equivariant MPNN forward (B=32, N=32, F=32, 9 sph comps, 2 parities, 3 iters)
// Inputs are FP32 (npz-size evidence: 116KB ~ f32 deflated; bf16 would be ~70KB).
// Output f32: energy[32] ++ dipole[32][3] = 128 floats.
// ============================================================================

// ---------------- compile-time CG table (exact port of _build_cg) ----------
namespace cgb {
constexpr double SQ2 = 1.4142135623730951;
constexpr double cabs_(double x){ return x < 0 ? -x : x; }
constexpr double fact(int n){ double r = 1.0; for (int i = 2; i <= n; ++i) r *= (double)i; return r; }
constexpr double csqrt(double x){
  if (x <= 0.0) return 0.0;
  double g = x > 1.0 ? x : 1.0;
  for (int i = 0; i < 48; ++i) g = 0.5 * (g + x / g);
  return g;
}
constexpr double cgc(int j1,int m1,int j2,int m2,int J,int M){
  if (m1 + m2 != M) return 0.0;
  int ad = j1 - j2; if (ad < 0) ad = -ad;
  if (J < ad || J > j1 + j2) return 0.0;
  double pref = (2.0*J+1.0) * fact(J+j1-j2) * fact(J-j1+j2) * fact(j1+j2-J) / fact(j1+j2+J+1);
  pref *= fact(J+M)*fact(J-M)*fact(j1-m1)*fact(j1+m1)*fact(j2-m2)*fact(j2+m2);
  double s = 0.0;
  for (int k = 0; k <= j1+j2; ++k){
    int d0=j1+j2-J-k, d1=j1-m1-k, d2=j2+m2-k, d3=J-j2+m1+k, d4=J-j1-m2+k;
    if (d0<0||d1<0||d2<0||d3<0||d4<0) continue;
    double t = 1.0/(fact(k)*fact(d0)*fact(d1)*fact(d2)*fact(d3)*fact(d4));
    s += (k & 1) ? -t : t;
  }
  return csqrt(pref) * s;
}
struct C2 { double re, im; };
struct URow { int n; int col[2]; C2 v[2]; };
constexpr URow urow(int l, int r){
  URow u{};
  if (r == l){ u.n = 1; u.col[0] = l; u.v[0] = C2{1.0, 0.0}; return u; }
  if (r > l){
    int m = r - l; double sg = (m & 1) ? -1.0 : 1.0;
    u.n = 2;
    u.col[0] = l + m; u.v[0] = C2{ sg / SQ2, 0.0 };
    u.col[1] = l - m; u.v[1] = C2{ 1.0 / SQ2, 0.0 };
    return u;
  }
  int m = l - r; double sg = (m & 1) ? -1.0 : 1.0;
  u.n = 2;
  u.col[0] = l - m; u.v[0] = C2{ 0.0, 1.0 / SQ2 };
  u.col[1] = l + m; u.v[1] = C2{ 0.0, -sg / SQ2 };   // -1j*(-1)^m/sqrt(2)
  return u;
}
struct Tab { float v[9][9][9]; };
constexpr Tab build(){
  Tab t{};
  for (int l1 = 0; l1 < 3; ++l1)
  for (int l2 = 0; l2 < 3; ++l2)
  for (int l3 = 0; l3 < 3; ++l3){
    int ad = l1 - l2; if (ad < 0) ad = -ad;
    if (l3 < ad || l3 > l1 + l2) continue;
    double C[5][5][5] = {};
    for (int m = 0; m < 2*l1+1; ++m)
      for (int n = 0; n < 2*l2+1; ++n){
        int o = (m - l1) + (n - l2) + l3;     // m-selection: m1+m2=M
        if (o < 0 || o > 2*l3) continue;
        C[m][n][o] = cgc(l1, m-l1, l2, n-l2, l3, o-l3);
      }
    for (int a = 0; a < 2*l1+1; ++a)
    for (int b = 0; b < 2*l2+1; ++b)
    for (int c = 0; c < 2*l3+1; ++c){
      URow ua = urow(l1,a), ub = urow(l2,b), uc = urow(l3,c);
      double gre = 0.0, gim = 0.0;
      for (int i = 0; i < ua.n; ++i)
      for (int j = 0; j < ub.n; ++j)
      for (int k = 0; k < uc.n; ++k){
        double Cv = C[ua.col[i]][ub.col[j]][uc.col[k]];
        if (Cv == 0.0) continue;
        double r1 = ua.v[i].re*ub.v[j].re - ua.v[i].im*ub.v[j].im;
        double i1 = ua.v[i].re*ub.v[j].im + ua.v[i].im*ub.v[j].re;
        double cr = uc.v[k].re, ci = -uc.v[k].im;  // conj(U3)
        gre += (r1*cr - i1*ci) * Cv;
        gim += (r1*ci + i1*cr) * Cv;
      }
      double r = (cabs_(gim) > cabs_(gre)) ? gim : gre;
      t.v[l1*l1+a][l2*l2+b][l3*l3+c] = (float)r;
    }
  }
  return t;
}
constexpr Tab CGT = build();
} // namespace cgb

constexpr int DM_[9] = {0,1,1,1,2,2,2,2,2};

// ---------------- compile-time for-each --------------------------------------
template<class F, int... Is>
__device__ __forceinline__ void sf_impl(F&& f, std::integer_sequence<int, Is...>){
  (f(std::integral_constant<int, Is>{}), ...);
}
template<int N, class F>
__device__ __forceinline__ void static_for(F&& f){
  sf_impl(static_cast<F&&>(f), std::make_integer_sequence<int, N>{});
}

// ---------------- device helpers ---------------------------------------------
__device__ __forceinline__ float rsum32(float v){
  #pragma unroll
  for (int s = 16; s > 0; s >>= 1) v += __shfl_xor(v, s, 32);
  return v;
}

__device__ __forceinline__ void silu18(float (&x)[2][9]){
  float gate = 1.0f / (1.0f + expf(-x[0][0]));
  #pragma unroll
  for (int p = 0; p < 2; ++p)
    #pragma unroll
    for (int m = 0; m < 9; ++m) x[p][m] *= gate;
}

// out[n,p,m,g] = sum_f x[n,p,m,f] * W[f,g]; lane holds feature index.
__device__ __forceinline__ void dense32(float (&x)[2][9], const float* W, int lane){
  float o[2][9];
  #pragma unroll
  for (int p = 0; p < 2; ++p)
    #pragma unroll
    for (int m = 0; m < 9; ++m){
      float acc = 0.0f;
      float xv = x[p][m];
      #pragma unroll 8
      for (int fp = 0; fp < 32; ++fp){
        float xb = __shfl(xv, fp, 32);
        acc = fmaf(xb, W[fp*32 + lane], acc);
      }
      o[p][m] = acc;
    }
  #pragma unroll
  for (int p = 0; p < 2; ++p)
    #pragma unroll
    for (int m = 0; m < 9; ++m) x[p][m] = o[p][m];
}

// _couple: p0 = cp(x1[0],x2[0]) + cp(x1[1],x2[1]);  p1 = cp(x1[0],x2[1]) + cp(x1[1],x2[0])
// cgw[a,b,c,f] = CG[a,b,c] * Wp[DM[a],DM[b],DM[c],f]  (wp = per-lane 27 path weights)
__device__ __forceinline__ void couple27(const float (&x1)[2][9], const float (&x2)[2][9],
                                         const float (&wp)[27], float (&p0)[9], float (&p1)[9]){
  #pragma unroll
  for (int c = 0; c < 9; ++c){ p0[c] = 0.0f; p1[c] = 0.0f; }
  static_for<729>([&](auto I){
    constexpr int idx = I.value, a = idx/81, b = (idx/9)%9, c = idx%9;
    constexpr float v = cgb::CGT.v[a][b][c];
    if constexpr (v != 0.0f){
      constexpr int path = (DM_[a]*3 + DM_[b])*3 + DM_[c];
      float w = v * wp[path];
      p0[c] = fmaf(w, fmaf(x1[0][a], x2[0][b], x1[1][a]*x2[1][b]), p0[c]);
      p1[c] = fmaf(w, fmaf(x1[0][a], x2[1][b], x1[1][a]*x2[0][b]), p1[c]);
    }
  });
}

// ---------------- kernels -----------------------------------------------------

// Per-edge geometry: sh[9], rad[8], r  -> EDATA[e][18]
__global__ __launch_bounds__(256) void k_edge(const float* __restrict__ POS,
                                              const int* __restrict__ dst_idx,
                                              const int* __restrict__ src_idx,
                                              float* __restrict__ ED,
                                              int Nn, int Eb, int E){
  int e = blockIdx.x*256 + threadIdx.x;
  if (e >= E) return;
  int bi = e / Eb, ei = e % Eb;
  int d = bi*Nn + dst_idx[ei];
  int s = bi*Nn + src_idx[ei];
  float dx = POS[s*3+0] - POS[d*3+0];
  float dy = POS[s*3+1] - POS[d*3+1];
  float dz = POS[s*3+2] - POS[d*3+2];
  float r  = sqrtf(dx*dx + dy*dy + dz*dz);
  float inv = 1.0f / (r + 1e-10f);
  float x = dx*inv, y = dy*inv, z = dz*inv;
  const float s3 = 1.7320508075688772f;
  float* o = ED + (size_t)e*18;
  o[0] = 1.0f; o[1] = y; o[2] = z; o[3] = x;
  o[4] = s3*x*y; o[5] = s3*y*z; o[6] = 0.5f*(3.0f*z*z - 1.0f);
  o[7] = s3*x*z; o[8] = 0.5f*s3*(x*x - y*y);
  // radial
  float fr = 1.0f / (1.0f + r);
  float om = 1.0f - fr;
  float frk[8]; frk[0] = 1.0f;
  #pragma unroll
  for (int k = 1; k < 8; ++k) frk[k] = frk[k-1]*fr;
  float omk[8]; omk[0] = 1.0f;
  #pragma unroll
  for (int k = 1; k < 8; ++k) omk[k] = omk[k-1]*om;
  const float bin[8] = {1.f,7.f,21.f,35.f,35.f,21.f,7.f,1.f};
  float u2 = (r*0.2f)*(r*0.2f);
  float cut = 0.0f;
  if (r < 5.0f){
    float den = fmaxf(1.0f - u2, 1e-6f);
    cut = expf(1.0f - 1.0f/den);
  }
  #pragma unroll
  for (int k = 0; k < 8; ++k) o[9+k] = bin[k]*frk[k]*omk[7-k]*cut;
  o[17] = r;
}

// x,xEF init
__global__ __launch_bounds__(256) void k_init(float* __restrict__ X, float* __restrict__ XEF,
                                              const int* __restrict__ Z,
                                              const float* __restrict__ embed,
                                              const float* __restrict__ Ef,
                                              int Nn, int BN){
  int t = blockIdx.x*256 + threadIdx.x;
  int n = t >> 5, f = t & 31;
  if (n >= BN) return;
  float* xp = X   + (size_t)n*576 + f;
  float* ep = XEF + (size_t)n*576 + f;
  #pragma unroll
  for (int j = 0; j < 18; ++j){ xp[j*32] = 0.0f; ep[j*32] = 0.0f; }
  xp[0] = embed[Z[n]*32 + f];
  int bi = n / Nn;
  float e0 = Ef[bi*3+0], e1 = Ef[bi*3+1], e2 = Ef[bi*3+2];
  ep[1*32] = e0; ep[2*32] = e1; ep[3*32] = e2;          // p=0, m=1..3
  ep[(9+1)*32] = e0; ep[(9+2)*32] = e1; ep[(9+3)*32] = e2; // p=1, m=1..3
}

// Message pass: one block (1 wave) per destination node; halves split 31 edges.
__global__ __launch_bounds__(64) void k_msg(const float* __restrict__ X,
                                            float* __restrict__ Y,
                                            const float* __restrict__ ED,
                                            const int* __restrict__ src_idx,
                                            const float* __restrict__ Wmp_i,   // (3,8,32)
                                            int Nn, int Eb, int md){
  __shared__ float wl[768];
  int tid = threadIdx.x;
  for (int j = tid; j < 768; j += 64) wl[j] = Wmp_i[j];
  __syncthreads();
  int n = blockIdx.x;
  int f = tid & 31, q = tid >> 5;
  int bi = n / Nn, d = n % Nn;
  int DEG = Nn - 1;
  float acc[2][9];
  #pragma unroll
  for (int p = 0; p < 2; ++p)
    #pragma unroll
    for (int c = 0; c < 9; ++c) acc[p][c] = 0.0f;

  for (int t = q; t < DEG; t += 2){
    int ei = d*DEG + t;                  // dst-sorted edge layout (meshgrid generator)
    int e  = bi*Eb + ei;
    const float* ed = ED + (size_t)e*18;
    float sh[9], rad[8];
    #pragma unroll
    for (int j = 0; j < 9; ++j) sh[j] = ed[j];
    #pragma unroll
    for (int j = 0; j < 8; ++j) rad[j] = ed[9+j];
    float wt0 = 0.f, wt1 = 0.f, wt2 = 0.f;
    #pragma unroll
    for (int nb = 0; nb < 8; ++nb){
      wt0 = fmaf(rad[nb], wl[(0*8+nb)*32 + f], wt0);
      wt1 = fmaf(rad[nb], wl[(1*8+nb)*32 + f], wt1);
      wt2 = fmaf(rad[nb], wl[(2*8+nb)*32 + f], wt2);
    }
    float g[9];
    g[0] = sh[0]*wt0;
    g[1] = sh[1]*wt1; g[2] = sh[2]*wt1; g[3] = sh[3]*wt1;
    g[4] = sh[4]*wt2; g[5] = sh[5]*wt2; g[6] = sh[6]*wt2;
    g[7] = sh[7]*wt2; g[8] = sh[8]*wt2;

    int s = bi*Nn + src_idx[ei];
    const float* xp = X + (size_t)s*576 + f;
    float xs[2][9];
    #pragma unroll
    for (int p = 0; p < 2; ++p)
      #pragma unroll
      for (int a = 0; a < 9; ++a) xs[p][a] = xp[(p*9+a)*32];

    static_for<729>([&](auto I){
      constexpr int idx = I.value, a = idx/81, b = (idx/9)%9, c = idx%9;
      constexpr float v = cgb::CGT.v[a][b][c];
      if constexpr (v != 0.0f){
        constexpr int pb = DM_[b] & 1;   // odd-degree g uses opposite-parity xs for y0
        float tg = v * g[b];
        acc[0][c] = fmaf(tg, xs[pb][a],     acc[0][c]);
        acc[1][c] = fmaf(tg, xs[pb ^ 1][a], acc[1][c]);
      }
    });
  }
  // combine the two halves
  #pragma unroll
  for (int p = 0; p < 2; ++p)
    #pragma unroll
    for (int c = 0; c < 9; ++c) acc[p][c] += __shfl_xor(acc[p][c], 32);

  if (q == 0){
    float* yp = Y + (size_t)n*576 + f;
    #pragma unroll
    for (int p = 0; p < 2; ++p)
      #pragma unroll
      for (int c = 0; c < 9; ++c){
        float vv = acc[p][c];
        if (md == 0 && c > 0) vv = 0.0f;   // degmask(0)
        yp[(p*9+c)*32] = vv;
      }
  }
}

// Per-node update for one iteration: 2 nodes per block (one per 32-lane half).
__global__ __launch_bounds__(64) void k_node(float* __restrict__ X, float* __restrict__ XEF,
                                             const float* __restrict__ Y,
                                             const float* __restrict__ Wd_i,
                                             const float* __restrict__ bd_i,
                                             const float* __restrict__ Wt_i,
                                             const float* __restrict__ Wtd1_i,
                                             const float* __restrict__ Wtd2_i,
                                             const float* __restrict__ Wtdp_i){
  __shared__ float lWd[1024], lW1[1024], lW2[1024];
  int tid = threadIdx.x;
  for (int j = tid; j < 1024; j += 64){ lWd[j] = Wd_i[j]; lW1[j] = Wtd1_i[j]; lW2[j] = Wtd2_i[j]; }
  __syncthreads();
  int n = blockIdx.x*2 + (tid >> 5);
  int f = tid & 31;
  float* xp = X   + (size_t)n*576 + f;
  float* ep = XEF + (size_t)n*576 + f;
  const float* yp = Y + (size_t)n*576 + f;

  float x[2][9], y[2][9], ef[2][9];
  #pragma unroll
  for (int p = 0; p < 2; ++p)
    #pragma unroll
    for (int m = 0; m < 9; ++m){
      x[p][m]  = xp[(p*9+m)*32];
      y[p][m]  = yp[(p*9+m)*32];
      ef[p][m] = ep[(p*9+m)*32];
    }
  // x += y ; silu
  #pragma unroll
  for (int p = 0; p < 2; ++p)
    #pragma unroll
    for (int m = 0; m < 9; ++m) x[p][m] += y[p][m];
  silu18(x);
  // dense(Wd) + bias at (0,0) ; silu
  dense32(x, lWd, f);
  x[0][0] += bd_i[f];
  silu18(x);
  // xEF = couple(x, xEF, Wt)
  float wpt[27];
  #pragma unroll
  for (int j = 0; j < 27; ++j) wpt[j] = Wt_i[j*32 + f];
  float p0[9], p1[9];
  couple27(x, ef, wpt, p0, p1);
  #pragma unroll
  for (int c = 0; c < 9; ++c){
    ep[(0*9+c)*32] = p0[c];
    ep[(1*9+c)*32] = p1[c];
    x[0][c] += p0[c];
    x[1][c] += p1[c];
  }
  // tensor_dense: u = x@Wtd1, v = x@Wtd2, x = couple(u, v, Wtdp)
  float u[2][9], v[2][9];
  #pragma unroll
  for (int p = 0; p < 2; ++p)
    #pragma unroll
    for (int m = 0; m < 9; ++m){ u[p][m] = x[p][m]; v[p][m] = x[p][m]; }
  dense32(u, lW1, f);
  dense32(v, lW2, f);
  float wp2[27];
  #pragma unroll
  for (int j = 0; j < 27; ++j) wp2[j] = Wtdp_i[j*32 + f];
  couple27(u, v, wp2, p0, p1);
  // x = coupled + y ; store
  #pragma unroll
  for (int c = 0; c < 9; ++c){
    xp[(0*9+c)*32] = p0[c] + y[0][c];
    xp[(1*9+c)*32] = p1[c] + y[1][c];
  }
}

// Readout head: 5 dense layers, charges, atomic dipoles, per-atom energies.
__global__ __launch_bounds__(64) void k_head(const float* __restrict__ X,
                                             const int* __restrict__ Z,
                                             const float* __restrict__ Wh,
                                             const float* __restrict__ bh,
                                             const float* __restrict__ Wq,
                                             const float* __restrict__ Wdip1,
                                             const float* __restrict__ Wdip2,
                                             const float* __restrict__ Wdipp,
                                             const float* __restrict__ wdip,
                                             const float* __restrict__ We,
                                             const float* __restrict__ be,
                                             const float* __restrict__ ebias,
                                             float* __restrict__ Q, float* __restrict__ AE,
                                             float* __restrict__ AD){
  __shared__ float lWh[5*1024];
  __shared__ float lW1[1024], lW2[1024];
  int tid = threadIdx.x;
  for (int j = tid; j < 5*1024; j += 64) lWh[j] = Wh[j];
  for (int j = tid; j < 1024; j += 64){ lW1[j] = Wdip1[j]; lW2[j] = Wdip2[j]; }
  __syncthreads();
  int n = blockIdx.x*2 + (tid >> 5);
  int f = tid & 31;
  const float* xp = X + (size_t)n*576 + f;
  float x[2][9];
  #pragma unroll
  for (int p = 0; p < 2; ++p)
    #pragma unroll
    for (int m = 0; m < 9; ++m) x[p][m] = xp[(p*9+m)*32];

  #pragma unroll
  for (int k = 0; k < 4; ++k){
    dense32(x, &lWh[k*1024], f);
    x[0][0] += bh[k*32 + f];
    silu18(x);
  }
  dense32(x, &lWh[4*1024], f);
  x[0][0] += bh[4*32 + f];

  float scal = x[0][0];
  float q  = rsum32(scal * Wq[f]);
  float ae = rsum32(scal * We[f]) + be[0] + ebias[Z[n]];

  // xd: keep (p0,m0) and (p1,m1..3), rest zero; tensor_dense with Wdip weights
  float xd[2][9];
  #pragma unroll
  for (int p = 0; p < 2; ++p)
    #pragma unroll
    for (int m = 0; m < 9; ++m) xd[p][m] = 0.0f;
  xd[0][0] = x[0][0];
  xd[1][1] = x[1][1]; xd[1][2] = x[1][2]; xd[1][3] = x[1][3];

  float u[2][9], v[2][9];
  #pragma unroll
  for (int p = 0; p < 2; ++p)
    #pragma unroll
    for (int m = 0; m < 9; ++m){ u[p][m] = xd[p][m]; v[p][m] = xd[p][m]; }
  dense32(u, lW1, f);
  dense32(v, lW2, f);
  float wp3[27];
  #pragma unroll
  for (int j = 0; j < 27; ++j) wp3[j] = Wdipp[j*32 + f];
  float p0[9], p1[9];
  couple27(u, v, wp3, p0, p1);
  // degmask(1): only c<=3 survive; we only need p1[1..3]
  float ad0 = rsum32(p1[1] * wdip[f]);
  float ad1 = rsum32(p1[2] * wdip[f]);
  float ad2 = rsum32(p1[3] * wdip[f]);

  if (f == 0){
    Q[n]  = q;
    AE[n] = ae;
    AD[3*n+0] = ad0; AD[3*n+1] = ad1; AD[3*n+2] = ad2;
  }
}

// Per-batch reduction: energy (+ Coulomb) and dipole.
__global__ __launch_bounds__(64) void k_final(const float* __restrict__ Q,
                                              const float* __restrict__ AE,
                                              const float* __restrict__ AD,
                                              const float* __restrict__ POS,
                                              const float* __restrict__ ED,
                                              const int* __restrict__ dst_idx,
                                              const int* __restrict__ src_idx,
                                              float* __restrict__ out,
                                              int Nn, int Eb, int Bv){
  __shared__ float qs[32];
  int b = blockIdx.x, tid = threadIdx.x;
  float q = 0.f, ae = 0.f, px = 0.f, py = 0.f, pz = 0.f, ax = 0.f, ay = 0.f, az = 0.f;
  if (tid < Nn){
    int n = b*Nn + tid;
    q  = Q[n]; ae = AE[n];
    px = POS[n*3+0]; py = POS[n*3+1]; pz = POS[n*3+2];
    ax = AD[3*n+0]; ay = AD[3*n+1]; az = AD[3*n+2];
    qs[tid] = q;
  }
  __syncthreads();
  float invN = 1.0f / (float)Nn;
  float cx = rsum32(px) * invN;
  float cy = rsum32(py) * invN;
  float cz = rsum32(pz) * invN;
  float dipx = rsum32(q*(px - cx) + ax);
  float dipy = rsum32(q*(py - cy) + ay);
  float dipz = rsum32(q*(pz - cz) + az);
  float sae  = rsum32(ae);

  // Coulomb over this batch's edges (all 64 lanes)
  float cl = 0.0f;
  for (int e = tid; e < Eb; e += 64){
    int dd = dst_idx[e], ss = src_idx[e];
    float r = ED[((size_t)b*Eb + e)*18 + 17];
    cl += qs[ss]*qs[dd] / (r + 1e-10f);
  }
  #pragma unroll
  for (int s = 32; s > 0; s >>= 1) cl += __shfl_xor(cl, s, 64);

  if (tid == 0){
    out[b] = sae + 0.5f*cl*14.399645f;
    out[Bv + b*3 + 0] = dipx;
    out[Bv + b*3 + 1] = dipy;
    out[Bv + b*3 + 2] = dipz;
  }
}

// ---------------- host launcher -----------------------------------------------
extern "C" void kernel_launch(void* const* d_in, const int* in_sizes, int n_in,
                              void* d_out, int out_size, void* d_ws, size_t ws_size,
                              hipStream_t stream) {
  (void)n_in; (void)out_size; (void)ws_size;
  const int*   Z     = (const int*)  d_in[0];
  const float* POS   = (const float*)d_in[1];
  const float* Ef    = (const float*)d_in[2];
  const int*   dst   = (const int*)  d_in[3];
  const int*   src   = (const int*)  d_in[4];
  // d_in[5] = batch_size (derived from sizes instead; no device read needed)
  const float* embed = (const float*)d_in[6];
  const float* Wmp   = (const float*)d_in[7];
  const float* Wd    = (const float*)d_in[8];
  const float* bd    = (const float*)d_in[9];
  const float* Wt    = (const float*)d_in[10];
  const float* Wtd1  = (const float*)d_in[11];
  const float* Wtd2  = (const float*)d_in[12];
  const float* Wtdp  = (const float*)d_in[13];
  const float* Wh    = (const float*)d_in[14];
  const float* bh    = (const float*)d_in[15];
  const float* Wq    = (const float*)d_in[16];
  const float* Wdip1 = (const float*)d_in[17];
  const float* Wdip2 = (const float*)d_in[18];
  const float* Wdipp = (const float*)d_in[19];
  const float* wdip  = (const float*)d_in[20];
  const float* We    = (const float*)d_in[21];
  const float* be    = (const float*)d_in[22];
  const float* ebias = (const float*)d_in[23];

  const int BN = in_sizes[0];        // 1024
  const int Bv = in_sizes[2] / 3;    // 32
  const int Nn = BN / Bv;            // 32
  const int Eb = in_sizes[3];        // 992
  const int E  = Bv * Eb;            // 31744

  float* wsf = (float*)d_ws;
  float* X   = wsf;
  float* XEF = X   + (size_t)BN*576;
  float* Y   = XEF + (size_t)BN*576;
  float* ED  = Y   + (size_t)BN*576;
  float* Qb  = ED  + (size_t)E*18;
  float* AEb = Qb  + BN;
  float* AD  = AEb + BN;

  k_edge<<<(E + 255)/256, 256, 0, stream>>>(POS, dst, src, ED, Nn, Eb, E);
  k_init<<<(BN*32 + 255)/256, 256, 0, stream>>>(X, XEF, Z, embed, Ef, Nn, BN);

  for (int i = 0; i < 3; ++i){
    int md = (i < 2) ? 2 : 0;
    k_msg<<<BN, 64, 0, stream>>>(X, Y, ED, src, Wmp + (size_t)i*768, Nn, Eb, md);
    k_node<<<BN/2, 64, 0, stream>>>(X, XEF, Y,
                                    Wd + (size_t)i*1024, bd + (size_t)i*32,
                                    Wt + (size_t)i*864,
                                    Wtd1 + (size_t)i*1024, Wtd2 + (size_t)i*1024,
                                    Wtdp + (size_t)i*864);
  }

  k_head<<<BN/2, 64, 0, stream>>>(X, Z, Wh, bh, Wq, Wdip1, Wdip2, Wdipp, wdip,
                                  We, be, ebias, Qb, AEb, AD);
  k_final<<<Bv, 64, 0, stream>>>(Qb, AEb, AD, POS, ED, dst, src,
                                 (float*)d_out, Nn, Eb, Bv);
}

// Round 2
// 167.398 us; speedup vs baseline: 1.2363x; 1.2363x over previous
//
#include <hip/hip_runtime.h>
#include <utility>
#include <type_traits>

// ============================================================================
// Equivariant MPNN forward (B=32, N=32, F=32, 9 sph comps, 2 parities, 3 iters)
// All float buffers f32. Output f32: energy[32] ++ dipole[32][3].
// R1: occupancy rework — k_msg 8 half-groups/node (4 waves/SIMD), k_node/k_head
// split 18 components across the two 32-lane halves of each wave.
// ============================================================================

// ---------------- compile-time CG table (exact port of _build_cg) ----------
namespace cgb {
constexpr double SQ2 = 1.4142135623730951;
constexpr double cabs_(double x){ return x < 0 ? -x : x; }
constexpr double fact(int n){ double r = 1.0; for (int i = 2; i <= n; ++i) r *= (double)i; return r; }
constexpr double csqrt(double x){
  if (x <= 0.0) return 0.0;
  double g = x > 1.0 ? x : 1.0;
  for (int i = 0; i < 48; ++i) g = 0.5 * (g + x / g);
  return g;
}
constexpr double cgc(int j1,int m1,int j2,int m2,int J,int M){
  if (m1 + m2 != M) return 0.0;
  int ad = j1 - j2; if (ad < 0) ad = -ad;
  if (J < ad || J > j1 + j2) return 0.0;
  double pref = (2.0*J+1.0) * fact(J+j1-j2) * fact(J-j1+j2) * fact(j1+j2-J) / fact(j1+j2+J+1);
  pref *= fact(J+M)*fact(J-M)*fact(j1-m1)*fact(j1+m1)*fact(j2-m2)*fact(j2+m2);
  double s = 0.0;
  for (int k = 0; k <= j1+j2; ++k){
    int d0=j1+j2-J-k, d1=j1-m1-k, d2=j2+m2-k, d3=J-j2+m1+k, d4=J-j1-m2+k;
    if (d0<0||d1<0||d2<0||d3<0||d4<0) continue;
    double t = 1.0/(fact(k)*fact(d0)*fact(d1)*fact(d2)*fact(d3)*fact(d4));
    s += (k & 1) ? -t : t;
  }
  return csqrt(pref) * s;
}
struct C2 { double re, im; };
struct URow { int n; int col[2]; C2 v[2]; };
constexpr URow urow(int l, int r){
  URow u{};
  if (r == l){ u.n = 1; u.col[0] = l; u.v[0] = C2{1.0, 0.0}; return u; }
  if (r > l){
    int m = r - l; double sg = (m & 1) ? -1.0 : 1.0;
    u.n = 2;
    u.col[0] = l + m; u.v[0] = C2{ sg / SQ2, 0.0 };
    u.col[1] = l - m; u.v[1] = C2{ 1.0 / SQ2, 0.0 };
    return u;
  }
  int m = l - r; double sg = (m & 1) ? -1.0 : 1.0;
  u.n = 2;
  u.col[0] = l - m; u.v[0] = C2{ 0.0, 1.0 / SQ2 };
  u.col[1] = l + m; u.v[1] = C2{ 0.0, -sg / SQ2 };
  return u;
}
struct Tab { float v[9][9][9]; };
constexpr Tab build(){
  Tab t{};
  for (int l1 = 0; l1 < 3; ++l1)
  for (int l2 = 0; l2 < 3; ++l2)
  for (int l3 = 0; l3 < 3; ++l3){
    int ad = l1 - l2; if (ad < 0) ad = -ad;
    if (l3 < ad || l3 > l1 + l2) continue;
    double C[5][5][5] = {};
    for (int m = 0; m < 2*l1+1; ++m)
      for (int n = 0; n < 2*l2+1; ++n){
        int o = (m - l1) + (n - l2) + l3;
        if (o < 0 || o > 2*l3) continue;
        C[m][n][o] = cgc(l1, m-l1, l2, n-l2, l3, o-l3);
      }
    for (int a = 0; a < 2*l1+1; ++a)
    for (int b = 0; b < 2*l2+1; ++b)
    for (int c = 0; c < 2*l3+1; ++c){
      URow ua = urow(l1,a), ub = urow(l2,b), uc = urow(l3,c);
      double gre = 0.0, gim = 0.0;
      for (int i = 0; i < ua.n; ++i)
      for (int j = 0; j < ub.n; ++j)
      for (int k = 0; k < uc.n; ++k){
        double Cv = C[ua.col[i]][ub.col[j]][uc.col[k]];
        if (Cv == 0.0) continue;
        double r1 = ua.v[i].re*ub.v[j].re - ua.v[i].im*ub.v[j].im;
        double i1 = ua.v[i].re*ub.v[j].im + ua.v[i].im*ub.v[j].re;
        double cr = uc.v[k].re, ci = -uc.v[k].im;
        gre += (r1*cr - i1*ci) * Cv;
        gim += (r1*ci + i1*cr) * Cv;
      }
      double r = (cabs_(gim) > cabs_(gre)) ? gim : gre;
      t.v[l1*l1+a][l2*l2+b][l3*l3+c] = (float)r;
    }
  }
  return t;
}
constexpr Tab CGT = build();
} // namespace cgb

constexpr int DM_[9] = {0,1,1,1,2,2,2,2,2};

// ---------------- compile-time for-each --------------------------------------
template<class F, int... Is>
__device__ __forceinline__ void sf_impl(F&& f, std::integer_sequence<int, Is...>){
  (f(std::integral_constant<int, Is>{}), ...);
}
template<int N, class F>
__device__ __forceinline__ void static_for(F&& f){
  sf_impl(static_cast<F&&>(f), std::make_integer_sequence<int, N>{});
}

// ---------------- device helpers ---------------------------------------------
__device__ __forceinline__ float rsum32(float v){
  #pragma unroll
  for (int s = 16; s > 0; s >>= 1) v += __shfl_xor(v, s, 32);
  return v;
}

// Half-split dense: each 32-lane half owns 9 comps; broadcast within half.
__device__ __forceinline__ void dense9(float (&x)[9], const float* __restrict__ W, int f){
  float o[9];
  #pragma unroll
  for (int m = 0; m < 9; ++m){
    float acc = 0.0f;
    float xv = x[m];
    #pragma unroll
    for (int fp = 0; fp < 32; ++fp)
      acc = fmaf(__shfl(xv, fp, 32), W[fp*32 + f], acc);
    o[m] = acc;
  }
  #pragma unroll
  for (int m = 0; m < 9; ++m) x[m] = o[m];
}

// silu on owned comps: gate from comp (0,0) (j=0, owned by half 0).
__device__ __forceinline__ void silu9(float (&x)[9], int q){
  float v0 = x[0];
  float w0 = __shfl_xor(v0, 32);
  float x00 = (q == 0) ? v0 : w0;
  float gate = 1.0f / (1.0f + expf(-x00));
  #pragma unroll
  for (int m = 0; m < 9; ++m) x[m] *= gate;
}

// Rebuild full [2][9] vector from 9 owned comps (j = 2*jj + q) via one exchange.
__device__ __forceinline__ void expand18(const float (&o)[9], int q, float (&xf)[2][9]){
  static_for<9>([&](auto J){
    constexpr int jj = J.value, je = 2*jj, jo = 2*jj + 1;
    float vv = o[jj];
    float ww = __shfl_xor(vv, 32);
    float ve = (q == 0) ? vv : ww;   // value at even comp je
    float vo = (q == 0) ? ww : vv;   // value at odd comp jo
    xf[je/9][je%9] = ve;
    xf[jo/9][jo%9] = vo;
  });
}

// _couple with per-lane 27 path weights; full inputs, full outputs.
__device__ __forceinline__ void couple27(const float (&x1)[2][9], const float (&x2)[2][9],
                                         const float (&wp)[27], float (&p0)[9], float (&p1)[9]){
  #pragma unroll
  for (int c = 0; c < 9; ++c){ p0[c] = 0.0f; p1[c] = 0.0f; }
  static_for<729>([&](auto I){
    constexpr int idx = I.value, a = idx/81, b = (idx/9)%9, c = idx%9;
    constexpr float v = cgb::CGT.v[a][b][c];
    if constexpr (v != 0.0f){
      constexpr int path = (DM_[a]*3 + DM_[b])*3 + DM_[c];
      float w = v * wp[path];
      p0[c] = fmaf(w, fmaf(x1[0][a], x2[0][b], x1[1][a]*x2[1][b]), p0[c]);
      p1[c] = fmaf(w, fmaf(x1[0][a], x2[1][b], x1[1][a]*x2[0][b]), p1[c]);
    }
  });
}

// ---------------- kernels -----------------------------------------------------

// Fused: per-edge geometry (sh[9], rad[8], r) + node-state init.
__global__ __launch_bounds__(256) void k_edge_init(const float* __restrict__ POS,
                                                   const int* __restrict__ dst_idx,
                                                   const int* __restrict__ src_idx,
                                                   float* __restrict__ ED,
                                                   const int* __restrict__ Z,
                                                   const float* __restrict__ embed,
                                                   const float* __restrict__ Ef,
                                                   float* __restrict__ X,
                                                   float* __restrict__ XEF,
                                                   int Nn, int Eb, int E, int BN){
  int t = blockIdx.x*256 + threadIdx.x;
  if (t < E){
    int e = t;
    int bi = e / Eb, ei = e % Eb;
    int d = bi*Nn + dst_idx[ei];
    int s = bi*Nn + src_idx[ei];
    float dx = POS[s*3+0] - POS[d*3+0];
    float dy = POS[s*3+1] - POS[d*3+1];
    float dz = POS[s*3+2] - POS[d*3+2];
    float r  = sqrtf(dx*dx + dy*dy + dz*dz);
    float inv = 1.0f / (r + 1e-10f);
    float x = dx*inv, y = dy*inv, z = dz*inv;
    const float s3 = 1.7320508075688772f;
    float* o = ED + (size_t)e*18;
    o[0] = 1.0f; o[1] = y; o[2] = z; o[3] = x;
    o[4] = s3*x*y; o[5] = s3*y*z; o[6] = 0.5f*(3.0f*z*z - 1.0f);
    o[7] = s3*x*z; o[8] = 0.5f*s3*(x*x - y*y);
    float fr = 1.0f / (1.0f + r);
    float om = 1.0f - fr;
    float frk[8]; frk[0] = 1.0f;
    #pragma unroll
    for (int k = 1; k < 8; ++k) frk[k] = frk[k-1]*fr;
    float omk[8]; omk[0] = 1.0f;
    #pragma unroll
    for (int k = 1; k < 8; ++k) omk[k] = omk[k-1]*om;
    const float bin[8] = {1.f,7.f,21.f,35.f,35.f,21.f,7.f,1.f};
    float u2 = (r*0.2f)*(r*0.2f);
    float cut = 0.0f;
    if (r < 5.0f){
      float den = fmaxf(1.0f - u2, 1e-6f);
      cut = expf(1.0f - 1.0f/den);
    }
    #pragma unroll
    for (int k = 0; k < 8; ++k) o[9+k] = bin[k]*frk[k]*omk[7-k]*cut;
    o[17] = r;
  } else {
    int u = t - E;
    if (u < BN*32){
      int n = u >> 5, f = u & 31;
      float* xp = X   + (size_t)n*576 + f;
      float* ep = XEF + (size_t)n*576 + f;
      #pragma unroll
      for (int j = 0; j < 18; ++j){ xp[j*32] = 0.0f; ep[j*32] = 0.0f; }
      xp[0] = embed[Z[n]*32 + f];
      int bi = n / Nn;
      float e0 = Ef[bi*3+0], e1 = Ef[bi*3+1], e2 = Ef[bi*3+2];
      ep[1*32] = e0; ep[2*32] = e1; ep[3*32] = e2;
      ep[(9+1)*32] = e0; ep[(9+2)*32] = e1; ep[(9+3)*32] = e2;
    }
  }
}

// Message pass: one block (8 half-groups of 32 lanes) per destination node.
__global__ __launch_bounds__(256, 4) void k_msg(const float* __restrict__ X,
                                                float* __restrict__ Y,
                                                const float* __restrict__ ED,
                                                const int* __restrict__ src_idx,
                                                const float* __restrict__ Wmp_i,   // (3,8,32)
                                                int Nn, int Eb, int md){
  __shared__ float wl[768];
  __shared__ float red[3][18][32];
  int tid = threadIdx.x;
  for (int j = tid; j < 768; j += 256) wl[j] = Wmp_i[j];
  __syncthreads();
  int n = blockIdx.x;
  int f = tid & 31, hg = tid >> 5;
  int bi = n / Nn, d = n % Nn;
  int DEG = Nn - 1;
  float acc[2][9];
  #pragma unroll
  for (int p = 0; p < 2; ++p)
    #pragma unroll
    for (int c = 0; c < 9; ++c) acc[p][c] = 0.0f;

  for (int t = hg; t < DEG; t += 8){
    int ei = d*DEG + t;                  // dst-sorted edge layout
    int e  = bi*Eb + ei;
    const float* ed = ED + (size_t)e*18;
    float sh[9], rad[8];
    #pragma unroll
    for (int j = 0; j < 9; ++j) sh[j] = ed[j];
    #pragma unroll
    for (int j = 0; j < 8; ++j) rad[j] = ed[9+j];
    float wt0 = 0.f, wt1 = 0.f, wt2 = 0.f;
    #pragma unroll
    for (int nb = 0; nb < 8; ++nb){
      wt0 = fmaf(rad[nb], wl[(0*8+nb)*32 + f], wt0);
      wt1 = fmaf(rad[nb], wl[(1*8+nb)*32 + f], wt1);
      wt2 = fmaf(rad[nb], wl[(2*8+nb)*32 + f], wt2);
    }
    float g[9];
    g[0] = sh[0]*wt0;
    g[1] = sh[1]*wt1; g[2] = sh[2]*wt1; g[3] = sh[3]*wt1;
    g[4] = sh[4]*wt2; g[5] = sh[5]*wt2; g[6] = sh[6]*wt2;
    g[7] = sh[7]*wt2; g[8] = sh[8]*wt2;

    int s = bi*Nn + src_idx[ei];
    const float* xp = X + (size_t)s*576 + f;
    float xs[2][9];
    #pragma unroll
    for (int p = 0; p < 2; ++p)
      #pragma unroll
      for (int a = 0; a < 9; ++a) xs[p][a] = xp[(p*9+a)*32];

    static_for<729>([&](auto I){
      constexpr int idx = I.value, a = idx/81, b = (idx/9)%9, c = idx%9;
      constexpr float v = cgb::CGT.v[a][b][c];
      if constexpr (v != 0.0f){
        constexpr int pb = DM_[b] & 1;
        float tg = v * g[b];
        acc[0][c] = fmaf(tg, xs[pb][a],     acc[0][c]);
        acc[1][c] = fmaf(tg, xs[pb ^ 1][a], acc[1][c]);
      }
    });
  }
  // combine pairs of half-groups within each wave
  #pragma unroll
  for (int p = 0; p < 2; ++p)
    #pragma unroll
    for (int c = 0; c < 9; ++c) acc[p][c] += __shfl_xor(acc[p][c], 32);

  int wave = tid >> 6;
  if (wave > 0 && (tid & 63) < 32){
    #pragma unroll
    for (int p = 0; p < 2; ++p)
      #pragma unroll
      for (int c = 0; c < 9; ++c) red[wave-1][p*9+c][f] = acc[p][c];
  }
  __syncthreads();
  if (tid < 32){
    float* yp = Y + (size_t)n*576 + f;
    #pragma unroll
    for (int p = 0; p < 2; ++p)
      #pragma unroll
      for (int c = 0; c < 9; ++c){
        float vv = acc[p][c] + red[0][p*9+c][f] + red[1][p*9+c][f] + red[2][p*9+c][f];
        if (md == 0 && c > 0) vv = 0.0f;
        yp[(p*9+c)*32] = vv;
      }
  }
}

// Per-node update: 4 nodes per 256-thread block; each node = 1 wave; the two
// 32-lane halves of the wave own the even/odd components (j = 2*jj + q).
__global__ __launch_bounds__(256) void k_node(float* __restrict__ X, float* __restrict__ XEF,
                                              const float* __restrict__ Y,
                                              const float* __restrict__ Wd_i,
                                              const float* __restrict__ bd_i,
                                              const float* __restrict__ Wt_i,
                                              const float* __restrict__ Wtd1_i,
                                              const float* __restrict__ Wtd2_i,
                                              const float* __restrict__ Wtdp_i){
  __shared__ float lWd[1024], lW1[1024], lW2[1024], lWt[864], lWp[864];
  int tid = threadIdx.x;
  for (int j = tid; j < 1024; j += 256){ lWd[j] = Wd_i[j]; lW1[j] = Wtd1_i[j]; lW2[j] = Wtd2_i[j]; }
  for (int j = tid; j < 864; j += 256){ lWt[j] = Wt_i[j]; lWp[j] = Wtdp_i[j]; }
  __syncthreads();
  int n = blockIdx.x*4 + (tid >> 6);
  int f = tid & 31;
  int q = (tid >> 5) & 1;
  float* xp = X   + (size_t)n*576 + f;
  float* ep = XEF + (size_t)n*576 + f;
  const float* yp = Y + (size_t)n*576 + f;

  float xo[9], yo[9], eo[9];
  #pragma unroll
  for (int jj = 0; jj < 9; ++jj){
    xo[jj] = xp[(2*jj+q)*32];
    yo[jj] = yp[(2*jj+q)*32];
    eo[jj] = ep[(2*jj+q)*32];
  }
  #pragma unroll
  for (int jj = 0; jj < 9; ++jj) xo[jj] += yo[jj];
  silu9(xo, q);
  dense9(xo, lWd, f);
  if (q == 0) xo[0] += bd_i[f];
  silu9(xo, q);

  // xEF = couple(x, xEF, Wt); x += new xEF
  float wpt[27];
  #pragma unroll
  for (int j = 0; j < 27; ++j) wpt[j] = lWt[j*32 + f];
  float xf[2][9], ef[2][9];
  expand18(xo, q, xf);
  expand18(eo, q, ef);
  float p0[9], p1[9];
  couple27(xf, ef, wpt, p0, p1);
  static_for<9>([&](auto J){
    constexpr int jj = J.value, je = 2*jj, jo = 2*jj + 1;
    float se = (je < 9) ? p0[je] : p1[je-9];
    float so = (jo < 9) ? p0[jo] : p1[jo-9];
    float s  = (q == 0) ? se : so;
    ep[(2*jj+q)*32] = s;
    xo[jj] += s;
  });

  // tensor_dense: u = x@Wtd1, v = x@Wtd2, x = couple(u, v, Wtdp) + y
  float u[9], v[9];
  #pragma unroll
  for (int jj = 0; jj < 9; ++jj){ u[jj] = xo[jj]; v[jj] = xo[jj]; }
  dense9(u, lW1, f);
  dense9(v, lW2, f);
  float wp2[27];
  #pragma unroll
  for (int j = 0; j < 27; ++j) wp2[j] = lWp[j*32 + f];
  float uf[2][9], vf[2][9];
  expand18(u, q, uf);
  expand18(v, q, vf);
  couple27(uf, vf, wp2, p0, p1);
  static_for<9>([&](auto J){
    constexpr int jj = J.value, je = 2*jj, jo = 2*jj + 1;
    float se = (je < 9) ? p0[je] : p1[je-9];
    float so = (jo < 9) ? p0[jo] : p1[jo-9];
    float s  = (q == 0) ? se : so;
    xp[(2*jj+q)*32] = s + yo[jj];
  });
}

// Readout head: 4 nodes per 256-thread block, half-split like k_node.
__global__ __launch_bounds__(256) void k_head(const float* __restrict__ X,
                                              const int* __restrict__ Z,
                                              const float* __restrict__ Wh,
                                              const float* __restrict__ bh,
                                              const float* __restrict__ Wq,
                                              const float* __restrict__ Wdip1,
                                              const float* __restrict__ Wdip2,
                                              const float* __restrict__ Wdipp,
                                              const float* __restrict__ wdip,
                                              const float* __restrict__ We,
                                              const float* __restrict__ be,
                                              const float* __restrict__ ebias,
                                              float* __restrict__ Q, float* __restrict__ AE,
                                              float* __restrict__ AD){
  __shared__ float lWh[5*1024];
  __shared__ float lW1[1024], lW2[1024], lWp[864];
  int tid = threadIdx.x;
  for (int j = tid; j < 5*1024; j += 256) lWh[j] = Wh[j];
  for (int j = tid; j < 1024; j += 256){ lW1[j] = Wdip1[j]; lW2[j] = Wdip2[j]; }
  for (int j = tid; j < 864; j += 256) lWp[j] = Wdipp[j];
  __syncthreads();
  int n = blockIdx.x*4 + (tid >> 6);
  int f = tid & 31;
  int q = (tid >> 5) & 1;
  const float* xp = X + (size_t)n*576 + f;
  float xo[9];
  #pragma unroll
  for (int jj = 0; jj < 9; ++jj) xo[jj] = xp[(2*jj+q)*32];

  #pragma unroll
  for (int k = 0; k < 4; ++k){
    dense9(xo, &lWh[k*1024], f);
    if (q == 0) xo[0] += bh[k*32 + f];
    silu9(xo, q);
  }
  dense9(xo, &lWh[4*1024], f);
  if (q == 0) xo[0] += bh[4*32 + f];

  float scal = xo[0];                       // valid on half 0
  float qv = rsum32(scal * Wq[f]);
  float ae = rsum32(scal * We[f]) + be[0] + ebias[Z[n]];

  // xd: keep j in {0, 10, 11, 12} (comp (0,0) and (1,1..3)); zero elsewhere.
  float xd[9];
  #pragma unroll
  for (int jj = 0; jj < 9; ++jj) xd[jj] = 0.0f;
  xd[0] = (q == 0) ? xo[0] : 0.0f;          // j=0
  xd[5] = xo[5];                            // j=10 (q0) / j=11 (q1) — both kept
  xd[6] = (q == 0) ? xo[6] : 0.0f;          // j=12

  float u[9], v[9];
  #pragma unroll
  for (int jj = 0; jj < 9; ++jj){ u[jj] = xd[jj]; v[jj] = xd[jj]; }
  dense9(u, lW1, f);
  dense9(v, lW2, f);
  float wp3[27];
  #pragma unroll
  for (int j = 0; j < 27; ++j) wp3[j] = lWp[j*32 + f];
  float uf[2][9], vf[2][9];
  expand18(u, q, uf);
  expand18(v, q, vf);
  float p0[9], p1[9];
  couple27(uf, vf, wp3, p0, p1);
  float ad0 = rsum32(p1[1] * wdip[f]);
  float ad1 = rsum32(p1[2] * wdip[f]);
  float ad2 = rsum32(p1[3] * wdip[f]);

  if (q == 0 && f == 0){
    Q[n]  = qv;
    AE[n] = ae;
    AD[3*n+0] = ad0; AD[3*n+1] = ad1; AD[3*n+2] = ad2;
  }
}

// Per-batch reduction: energy (+ Coulomb) and dipole.
__global__ __launch_bounds__(64) void k_final(const float* __restrict__ Q,
                                              const float* __restrict__ AE,
                                              const float* __restrict__ AD,
                                              const float* __restrict__ POS,
                                              const float* __restrict__ ED,
                                              const int* __restrict__ dst_idx,
                                              const int* __restrict__ src_idx,
                                              float* __restrict__ out,
                                              int Nn, int Eb, int Bv){
  __shared__ float qs[32];
  int b = blockIdx.x, tid = threadIdx.x;
  float q = 0.f, ae = 0.f, px = 0.f, py = 0.f, pz = 0.f, ax = 0.f, ay = 0.f, az = 0.f;
  if (tid < Nn){
    int n = b*Nn + tid;
    q  = Q[n]; ae = AE[n];
    px = POS[n*3+0]; py = POS[n*3+1]; pz = POS[n*3+2];
    ax = AD[3*n+0]; ay = AD[3*n+1]; az = AD[3*n+2];
    qs[tid] = q;
  }
  __syncthreads();
  float invN = 1.0f / (float)Nn;
  float cx = rsum32(px) * invN;
  float cy = rsum32(py) * invN;
  float cz = rsum32(pz) * invN;
  float dipx = rsum32(q*(px - cx) + ax);
  float dipy = rsum32(q*(py - cy) + ay);
  float dipz = rsum32(q*(pz - cz) + az);
  float sae  = rsum32(ae);

  float cl = 0.0f;
  for (int e = tid; e < Eb; e += 64){
    int dd = dst_idx[e], ss = src_idx[e];
    float r = ED[((size_t)b*Eb + e)*18 + 17];
    cl += qs[ss]*qs[dd] / (r + 1e-10f);
  }
  #pragma unroll
  for (int s = 32; s > 0; s >>= 1) cl += __shfl_xor(cl, s, 64);

  if (tid == 0){
    out[b] = sae + 0.5f*cl*14.399645f;
    out[Bv + b*3 + 0] = dipx;
    out[Bv + b*3 + 1] = dipy;
    out[Bv + b*3 + 2] = dipz;
  }
}

// ---------------- host launcher -----------------------------------------------
extern "C" void kernel_launch(void* const* d_in, const int* in_sizes, int n_in,
                              void* d_out, int out_size, void* d_ws, size_t ws_size,
                              hipStream_t stream) {
  (void)n_in; (void)out_size; (void)ws_size;
  const int*   Z     = (const int*)  d_in[0];
  const float* POS   = (const float*)d_in[1];
  const float* Ef    = (const float*)d_in[2];
  const int*   dst   = (const int*)  d_in[3];
  const int*   src   = (const int*)  d_in[4];
  const float* embed = (const float*)d_in[6];
  const float* Wmp   = (const float*)d_in[7];
  const float* Wd    = (const float*)d_in[8];
  const float* bd    = (const float*)d_in[9];
  const float* Wt    = (const float*)d_in[10];
  const float* Wtd1  = (const float*)d_in[11];
  const float* Wtd2  = (const float*)d_in[12];
  const float* Wtdp  = (const float*)d_in[13];
  const float* Wh    = (const float*)d_in[14];
  const float* bh    = (const float*)d_in[15];
  const float* Wq    = (const float*)d_in[16];
  const float* Wdip1 = (const float*)d_in[17];
  const float* Wdip2 = (const float*)d_in[18];
  const float* Wdipp = (const float*)d_in[19];
  const float* wdip  = (const float*)d_in[20];
  const float* We    = (const float*)d_in[21];
  const float* be    = (const float*)d_in[22];
  const float* ebias = (const float*)d_in[23];

  const int BN = in_sizes[0];        // 1024
  const int Bv = in_sizes[2] / 3;    // 32
  const int Nn = BN / Bv;            // 32
  const int Eb = in_sizes[3];        // 992
  const int E  = Bv * Eb;            // 31744

  float* wsf = (float*)d_ws;
  float* X   = wsf;
  float* XEF = X   + (size_t)BN*576;
  float* Y   = XEF + (size_t)BN*576;
  float* ED  = Y   + (size_t)BN*576;
  float* Qb  = ED  + (size_t)E*18;
  float* AEb = Qb  + BN;
  float* AD  = AEb + BN;

  int total = E + BN*32;
  k_edge_init<<<(total + 255)/256, 256, 0, stream>>>(POS, dst, src, ED, Z, embed, Ef,
                                                     X, XEF, Nn, Eb, E, BN);

  for (int i = 0; i < 3; ++i){
    int md = (i < 2) ? 2 : 0;
    k_msg<<<BN, 256, 0, stream>>>(X, Y, ED, src, Wmp + (size_t)i*768, Nn, Eb, md);
    k_node<<<BN/4, 256, 0, stream>>>(X, XEF, Y,
                                     Wd + (size_t)i*1024, bd + (size_t)i*32,
                                     Wt + (size_t)i*864,
                                     Wtd1 + (size_t)i*1024, Wtd2 + (size_t)i*1024,
                                     Wtdp + (size_t)i*864);
  }

  k_head<<<BN/4, 256, 0, stream>>>(X, Z, Wh, bh, Wq, Wdip1, Wdip2, Wdipp, wdip,
                                   We, be, ebias, Qb, AEb, AD);
  k_final<<<Bv, 64, 0, stream>>>(Qb, AEb, AD, POS, ED, dst, src,
                                 (float*)d_out, Nn, Eb, Bv);
}